// Round 2
// baseline (17730.405 us; speedup 1.0000x reference)
//
#include <hip/hip_runtime.h>
#include <stdint.h>

// RNN_Stack: 3-layer leaky-integrator RNN, T=512, B=256, I=64, N=512, TAU=2.
//
// Round-2 design: INTRA-CU RECURRENCE. 48 blocks = 3 stages (layers) x 16 row
// slices, 1024 threads (16 waves) per block, 1 block/CU. Each block owns
// [16 rows x ALL 512 cols] of its layer: the recurrence h@Whh never leaves the
// CU (h round-trips through LDS double-buffer; Whh/Whi/Win column slices are
// VGPR-resident B-fragments, ~350 VGPRs/lane at 4 waves/SIMD).
// Only the feed-forward n_{l-1} -> layer l link crosses CUs: point-to-point
// ring + monotonic prod/done counters (release/acquire agent atomics). Stage l
// trails stage l-1, so its poll is pre-satisfied (pipeline slack hides LLC
// latency); no intra-stage sync exists at all.

#define TS    512
#define BB    256
#define NN    512
#define MR    16     // rows per slice
#define NS    16     // slices
#define RD    8      // ring depth (steps)
#define LROW  520    // padded LDS row stride (shorts): lo-stride 1040B -> 2-way banks (free)

typedef __attribute__((ext_vector_type(8))) short s8v;    // 8 bf16 (4 VGPR)
typedef __attribute__((ext_vector_type(4))) float f4v;    // 4 f32

#define MFMA16(a, b, c) __builtin_amdgcn_mfma_f32_16x16x32_bf16((a), (b), (c), 0, 0, 0)

__device__ __forceinline__ short f2bf(float f) {  // RNE f32 -> bf16 bits
  union { float f; unsigned u; } v; v.f = f;
  unsigned u = v.u;
  u += 0x7fffu + ((u >> 16) & 1u);
  return (short)(u >> 16);
}

__device__ __forceinline__ s8v pack8(f4v a, f4v b) {
  s8v v;
  v[0] = f2bf(a[0]); v[1] = f2bf(a[1]); v[2] = f2bf(a[2]); v[3] = f2bf(a[3]);
  v[4] = f2bf(b[0]); v[5] = f2bf(b[1]); v[6] = f2bf(b[2]); v[7] = f2bf(b[3]);
  return v;
}

__global__ __launch_bounds__(1024, 4) void rnn_pipe(
    const float* __restrict__ data, const float* __restrict__ h0,
    const float* __restrict__ Win,  const float* __restrict__ b_in,
    const float* __restrict__ Whh,  const float* __restrict__ b_hh,
    const float* __restrict__ Whi,  const float* __restrict__ b_hi,
    unsigned short* __restrict__ ring, unsigned* __restrict__ cnt,
    float* __restrict__ hfinal)
{
  __shared__ __attribute__((aligned(16))) unsigned short hbuf[2][MR * LROW];

  const int bi   = blockIdx.x;
  const int lay  = bi % 3;
  const int sl   = bi / 3;
  const int tid  = threadIdx.x;
  const int wv   = tid >> 6;        // 0..15
  const int lane = tid & 63;
  const int lo   = lane & 15;
  const int q4   = lane >> 4;
  const int row0 = sl * MR;
  const int cw   = wv * 32;         // this wave's 32-col base

  // monotonic counters, 128B-strided to avoid false sharing
  unsigned* prod_self = cnt + (size_t)(lay * NS + sl) * 32;          // lay<2 writes
  unsigned* prod_up   = cnt + (size_t)((lay - 1) * NS + sl) * 32;    // lay>0 polls
  unsigned* done_self = cnt + (size_t)(64 + (lay - 1) * NS + sl) * 32; // lay>0 writes
  unsigned* done_down = cnt + (size_t)(64 + lay * NS + sl) * 32;       // lay<2 polls

  // ---- weight preload: B-frag[k = kk*32 + q4*8 + j][col = cw + nf*16 + lo] ----
  s8v WH[16][2];            // Whh_lay (diag zeroed)
  s8v WI[16][2];            // Whi_{lay-1} (lay>0)
  s8v WX[2][2];             // Win (K=64)
  float biasv[2];
  f4v  hst[2];              // f32 h-state, C-layout rows q4*4+r, cols cw+nf*16+lo

  {
    const float* WmH = Whh + (size_t)lay * NN * NN;
    #pragma unroll
    for (int kk = 0; kk < 16; ++kk) {
      #pragma unroll
      for (int nf = 0; nf < 2; ++nf) {
        const int col = cw + nf * 16 + lo;
        s8v v;
        #pragma unroll
        for (int j = 0; j < 8; ++j) {
          const int k = kk * 32 + q4 * 8 + j;
          float f = WmH[(size_t)k * NN + col];
          if (k == col) f = 0.f;            // forward() zeroes recurrent diag
          v[j] = f2bf(f);
        }
        WH[kk][nf] = v;
      }
    }
    if (lay > 0) {
      const float* WmI = Whi + (size_t)(lay - 1) * NN * NN;
      #pragma unroll
      for (int kk = 0; kk < 16; ++kk) {
        #pragma unroll
        for (int nf = 0; nf < 2; ++nf) {
          const int col = cw + nf * 16 + lo;
          s8v v;
          #pragma unroll
          for (int j = 0; j < 8; ++j)
            v[j] = f2bf(WmI[(size_t)(kk * 32 + q4 * 8 + j) * NN + col]);
          WI[kk][nf] = v;
        }
      }
    }
    #pragma unroll
    for (int kk = 0; kk < 2; ++kk) {
      #pragma unroll
      for (int nf = 0; nf < 2; ++nf) {
        const int col = cw + nf * 16 + lo;
        s8v v;
        #pragma unroll
        for (int j = 0; j < 8; ++j)
          v[j] = f2bf(Win[(size_t)(kk * 32 + q4 * 8 + j) * NN + col]);
        WX[kk][nf] = v;
      }
    }
    #pragma unroll
    for (int nf = 0; nf < 2; ++nf) {
      const int col = cw + nf * 16 + lo;
      float b = b_hh[lay * NN + col] + b_in[col];
      if (lay > 0) b += b_hi[(lay - 1) * NN + col];
      biasv[nf] = b;
      #pragma unroll
      for (int r = 0; r < 4; ++r)
        hst[nf][r] = h0[(size_t)lay * BB * NN + (size_t)(row0 + q4 * 4 + r) * NN + col];
    }
  }

  const unsigned short* up_base =
      (lay > 0) ? ring + (size_t)((lay - 1) * NS + sl) * RD * (MR * NN) : nullptr;
  unsigned short* my_base =
      (lay < 2) ? ring + (size_t)(lay * NS + sl) * RD * (MR * NN) : nullptr;

  int cur = 0;
  for (int t = 0; t < TS; ++t) {
    const int slot = t & (RD - 1);

    // ---- Phase W: point-to-point waits (usually pre-satisfied in steady state)
    if (tid == 0) {
      if (lay > 0) {
        while (__hip_atomic_load(prod_up, __ATOMIC_ACQUIRE, __HIP_MEMORY_SCOPE_AGENT)
               < (unsigned)(t + 1))
          __builtin_amdgcn_s_sleep(2);
      }
      if (lay < 2 && t >= RD) {
        while (__hip_atomic_load(done_down, __ATOMIC_RELAXED, __HIP_MEMORY_SCOPE_AGENT)
               < (unsigned)(t - RD + 1))
          __builtin_amdgcn_s_sleep(2);
      }
    }
    __syncthreads();

    // ---- Phase C: acc = x-part + p-part + q-part
    f4v zero4 = {0.f, 0.f, 0.f, 0.f};
    f4v acc[2] = {zero4, zero4};

    // x = data(t) @ Win  (K=64; A-frags read f32, packed to bf16; L1/L2-hot)
    {
      const float* dsrc = data + ((size_t)t * BB + row0 + lo) * 64 + q4 * 8;
      #pragma unroll
      for (int kk = 0; kk < 2; ++kk) {
        f4v a = *(const f4v*)(dsrc + kk * 32);
        f4v b = *(const f4v*)(dsrc + kk * 32 + 4);
        s8v av = pack8(a, b);
        acc[0] = MFMA16(av, WX[kk][0], acc[0]);
        acc[1] = MFMA16(av, WX[kk][1], acc[1]);
      }
    }

    // p = n_{l-1}(t) @ Whi  (A-frags straight from upstream ring; LLC/L2)
    if (lay > 0) {
      const unsigned short* psrc = up_base + (size_t)slot * (MR * NN) + (size_t)lo * NN + q4 * 8;
      #pragma unroll
      for (int kk = 0; kk < 16; ++kk) {
        s8v av = *(const s8v*)(psrc + kk * 32);
        acc[0] = MFMA16(av, WI[kk][0], acc[0]);
        acc[1] = MFMA16(av, WI[kk][1], acc[1]);
      }
    }

    // q = h_l(t-1) @ Whh  (A-frags from LDS double-buffer; t=0 from h0)
    if (t == 0) {
      const float* hsrc = h0 + (size_t)lay * BB * NN + (size_t)(row0 + lo) * NN + q4 * 8;
      #pragma unroll
      for (int kk = 0; kk < 16; ++kk) {
        f4v a = *(const f4v*)(hsrc + kk * 32);
        f4v b = *(const f4v*)(hsrc + kk * 32 + 4);
        s8v av = pack8(a, b);
        acc[0] = MFMA16(av, WH[kk][0], acc[0]);
        acc[1] = MFMA16(av, WH[kk][1], acc[1]);
      }
    } else {
      const unsigned short* hs = hbuf[cur] + lo * LROW + q4 * 8;
      #pragma unroll
      for (int kk = 0; kk < 16; ++kk) {
        s8v av = *(const s8v*)(hs + kk * 32);
        acc[0] = MFMA16(av, WH[kk][0], acc[0]);
        acc[1] = MFMA16(av, WH[kk][1], acc[1]);
      }
    }

    // ---- Phase F: combine, write LDS next-buffer + ring, publish
    {
      unsigned short* rslot = (lay < 2) ? my_base + (size_t)slot * (MR * NN) : nullptr;
      unsigned short* lds   = hbuf[cur ^ 1];
      #pragma unroll
      for (int nf = 0; nf < 2; ++nf) {
        const int col = cw + nf * 16 + lo;
        #pragma unroll
        for (int r = 0; r < 4; ++r) {
          const int row = q4 * 4 + r;
          float v = 0.5f * hst[nf][r] + 0.5f * (acc[nf][r] + biasv[nf]);
          v = (v >= 0.f) ? v : 0.01f * v;
          hst[nf][r] = v;
          const unsigned short bv = (unsigned short)f2bf(v);
          lds[row * LROW + col] = bv;
          if (lay < 2) rslot[(size_t)row * NN + col] = bv;
          if (lay == 2 && t == TS - 1)
            hfinal[(size_t)(row0 + row) * NN + col] = v;
        }
      }
    }
    __syncthreads();  // drains vmcnt/lgkmcnt of every wave before publishing
    if (tid == 0) {
      if (lay < 2)
        __hip_atomic_store(prod_self, (unsigned)(t + 1), __ATOMIC_RELEASE,
                           __HIP_MEMORY_SCOPE_AGENT);
      if (lay > 0)
        __hip_atomic_store(done_self, (unsigned)(t + 1), __ATOMIC_RELAXED,
                           __HIP_MEMORY_SCOPE_AGENT);
    }
    cur ^= 1;
  }
}

// out[256,10] = hfinal @ Wfc + b_fc   (tiny f32 readout)
__global__ void readout_k(const float* __restrict__ hfinal, const float* __restrict__ Wfc,
                          const float* __restrict__ b_fc, float* __restrict__ out)
{
  const int row = blockIdx.x;
  const int lane = threadIdx.x;  // 64
  float a[10];
  #pragma unroll
  for (int c = 0; c < 10; ++c) a[c] = 0.f;
  for (int k = lane; k < NN; k += 64) {
    const float h = hfinal[(size_t)row * NN + k];
    const float* w = Wfc + (size_t)k * 10;
    #pragma unroll
    for (int c = 0; c < 10; ++c) a[c] += h * w[c];
  }
  #pragma unroll
  for (int off = 32; off > 0; off >>= 1) {
    #pragma unroll
    for (int c = 0; c < 10; ++c) a[c] += __shfl_down(a[c], off);
  }
  if (lane == 0) {
    #pragma unroll
    for (int c = 0; c < 10; ++c) out[row * 10 + c] = a[c] + b_fc[c];
  }
}

extern "C" void kernel_launch(void* const* d_in, const int* in_sizes, int n_in,
                              void* d_out, int out_size, void* d_ws, size_t ws_size,
                              hipStream_t stream) {
  (void)in_sizes; (void)n_in; (void)out_size; (void)ws_size;
  const float* data = (const float*)d_in[0];
  const float* h0   = (const float*)d_in[1];
  const float* Win  = (const float*)d_in[2];
  const float* b_in = (const float*)d_in[3];
  const float* Whh  = (const float*)d_in[4];
  const float* b_hh = (const float*)d_in[5];
  const float* Whi  = (const float*)d_in[6];
  const float* b_hi = (const float*)d_in[7];
  const float* Wfc  = (const float*)d_in[8];
  const float* b_fc = (const float*)d_in[9];

  // ws layout: rings (2 producer layers x 16 slices x RD x 16KB = 4 MB)
  //          | cnt (128 entries x 128 B = 16 KB, 64 KB zone) | hfinal (512 KB)
  unsigned short* ring = (unsigned short*)d_ws;
  const size_t ring_bytes = (size_t)2 * NS * RD * MR * NN * 2;  // 4 MB
  unsigned* cnt = (unsigned*)((char*)d_ws + ring_bytes);
  const size_t cnt_bytes = 128 * 128;                            // 16 KB
  float* hfinal = (float*)((char*)d_ws + ring_bytes + 65536);

  hipMemsetAsync(cnt, 0, cnt_bytes, stream);
  hipLaunchKernelGGL(rnn_pipe, dim3(48), dim3(1024), 0, stream,
                     data, h0, Win, b_in, Whh, b_hh, Whi, b_hi, ring, cnt, hfinal);
  hipLaunchKernelGGL(readout_k, dim3(256), dim3(64), 0, stream,
                     hfinal, Wfc, b_fc, (float*)d_out);
}

// Round 3
// 2380.922 us; speedup vs baseline: 7.4469x; 7.4469x over previous
//
#include <hip/hip_runtime.h>
#include <stdint.h>

// RNN_Stack: 3-layer leaky-integrator RNN, T=512, B=256, I=64, N=512, TAU=2.
//
// Round-3: round-0's register-resident-weight structure + fence-free sc1
// producer/consumer protocol.
//   192 blocks = 3 layers x 16 rowgroups x 4 coltiles; 256 thr (4 waves,
//   1 wave/SIMD -> 512-VGPR budget). Each wave owns 32 cols and holds
//   Whh/Whi/Win column-slice B-fragments in VGPRs (~270 regs); each block
//   computes a [16 row x 128 col] tile of one layer for all T steps.
//   Cross-CU handoff (h-broadcast within a layer + feed-forward to next
//   layer) goes through LLC ring buffers accessed ONLY with sc1 (L2-bypass)
//   loads/stores, so no __threadfence (no buffer_wbl2 / buffer_inv) is ever
//   needed: release ordering = vmcnt(0) drain in __syncthreads + relaxed
//   agent-scope flag store; acquire = control dependency on the flag poll.

#define TS    512
#define BB    256
#define NN    512
#define MR    16     // rows per block
#define NRG   16     // rowgroups
#define NCT   4      // coltiles per layer
#define RD    8      // ring depth (steps)
#define LROW  520    // padded LDS row stride (shorts)

typedef __attribute__((ext_vector_type(8))) short s8v;    // 8 bf16 (4 VGPR)
typedef __attribute__((ext_vector_type(4))) float f4v;    // 4 f32
typedef __attribute__((ext_vector_type(4))) unsigned int u4v;

#define MFMA16(a, b, c) __builtin_amdgcn_mfma_f32_16x16x32_bf16((a), (b), (c), 0, 0, 0)

__device__ __forceinline__ short f2bf(float f) {  // RNE f32 -> bf16 bits
  union { float f; unsigned u; } v; v.f = f;
  unsigned u = v.u;
  u += 0x7fffu + ((u >> 16) & 1u);
  return (short)(u >> 16);
}

__device__ __forceinline__ s8v pack8(f4v a, f4v b) {
  s8v v;
  v[0] = f2bf(a[0]); v[1] = f2bf(a[1]); v[2] = f2bf(a[2]); v[3] = f2bf(a[3]);
  v[4] = f2bf(b[0]); v[5] = f2bf(b[1]); v[6] = f2bf(b[2]); v[7] = f2bf(b[3]);
  return v;
}

// sc1 = bypass XCD L2, hit the device coherence point (LLC) directly.
__device__ __forceinline__ u4v ldg_sc1_x4(const unsigned short* p) {
  u4v r;
  asm volatile("global_load_dwordx4 %0, %1, off sc1" : "=v"(r) : "v"(p));
  return r;
}
__device__ __forceinline__ void stg_sc1_b16(unsigned short* p, unsigned v) {
  asm volatile("global_store_short %0, %1, off sc1" :: "v"(p), "v"(v) : "memory");
}
__device__ __forceinline__ void waitvm0() {
  asm volatile("s_waitcnt vmcnt(0)" ::: "memory");
}

__global__ __launch_bounds__(256, 1) void rnn_pipe(
    const float* __restrict__ data, const float* __restrict__ h0,
    const float* __restrict__ Win,  const float* __restrict__ b_in,
    const float* __restrict__ Whh,  const float* __restrict__ b_hh,
    const float* __restrict__ Whi,  const float* __restrict__ b_hi,
    unsigned short* __restrict__ ring, unsigned* __restrict__ cnt,
    float* __restrict__ hfinal)
{
  __shared__ __attribute__((aligned(16))) unsigned short qtile[MR * LROW];
  __shared__ __attribute__((aligned(16))) unsigned short ptile[MR * LROW];

  const int bi   = blockIdx.x;
  const int lay  = bi % 3;
  const int rest = bi / 3;        // 0..63
  const int rg   = rest & 15;
  const int ct   = rest >> 4;     // 0..3
  const int tid  = threadIdx.x;
  const int wv   = tid >> 6;
  const int lane = tid & 63;
  const int lo   = lane & 15;
  const int q4   = lane >> 4;
  const int row0 = rg * MR;
  const int cw   = ct * 128 + wv * 32;   // this wave's 32-col base

  // ---- flags: prod[idx], done[idx] at 128B stride; idx=(lay*16+rg)*4+ct ----
  const int sidx = (lay * NRG + rg) * NCT + ct;
  unsigned* selfprod = cnt + (size_t)sidx * 32;
  unsigned* selfdone = cnt + (size_t)(256 + sidx) * 32;

  // per-lane poll assignment (lanes 0-3: q-join, 4-7: p-join, 8-11: backpressure)
  unsigned* pollptr = selfprod;   // dummy (target stays 0)
  int polltype = 0;
  if (lane < 4) {
    pollptr = cnt + (size_t)((lay * NRG + rg) * NCT + lane) * 32;  polltype = 1;
  } else if (lane >= 4 && lane < 8 && lay > 0) {
    pollptr = cnt + (size_t)(((lay - 1) * NRG + rg) * NCT + (lane - 4)) * 32;  polltype = 2;
  } else if (lane >= 8 && lane < 12 && lay < 2) {
    pollptr = cnt + (size_t)(256 + ((lay + 1) * NRG + rg) * NCT + (lane - 8)) * 32;  polltype = 3;
  }

  // ---- weight preload: B-frag[k = kk*32 + q4*8 + j][col = cw + nf*16 + lo] ----
  s8v WH[16][2];            // Whh_lay (diag zeroed)
  s8v WI[16][2];            // Whi_{lay-1} (lay>0)
  s8v WX[2][2];             // Win (K=64)
  float biasv[2];
  f4v  hst[2];              // f32 h-state, C-layout rows q4*4+r, cols cw+nf*16+lo

  {
    const float* WmH = Whh + (size_t)lay * NN * NN;
    #pragma unroll
    for (int kk = 0; kk < 16; ++kk) {
      #pragma unroll
      for (int nf = 0; nf < 2; ++nf) {
        const int col = cw + nf * 16 + lo;
        s8v v;
        #pragma unroll
        for (int j = 0; j < 8; ++j) {
          const int k = kk * 32 + q4 * 8 + j;
          float f = WmH[(size_t)k * NN + col];
          if (k == col) f = 0.f;            // forward() zeroes recurrent diag
          v[j] = f2bf(f);
        }
        WH[kk][nf] = v;
      }
    }
    if (lay > 0) {
      const float* WmI = Whi + (size_t)(lay - 1) * NN * NN;
      #pragma unroll
      for (int kk = 0; kk < 16; ++kk) {
        #pragma unroll
        for (int nf = 0; nf < 2; ++nf) {
          const int col = cw + nf * 16 + lo;
          s8v v;
          #pragma unroll
          for (int j = 0; j < 8; ++j)
            v[j] = f2bf(WmI[(size_t)(kk * 32 + q4 * 8 + j) * NN + col]);
          WI[kk][nf] = v;
        }
      }
    }
    #pragma unroll
    for (int kk = 0; kk < 2; ++kk) {
      #pragma unroll
      for (int nf = 0; nf < 2; ++nf) {
        const int col = cw + nf * 16 + lo;
        s8v v;
        #pragma unroll
        for (int j = 0; j < 8; ++j)
          v[j] = f2bf(Win[(size_t)(kk * 32 + q4 * 8 + j) * NN + col]);
        WX[kk][nf] = v;
      }
    }
    #pragma unroll
    for (int nf = 0; nf < 2; ++nf) {
      const int col = cw + nf * 16 + lo;
      float b = b_hh[lay * NN + col] + b_in[col];
      if (lay > 0) b += b_hi[(lay - 1) * NN + col];
      biasv[nf] = b;
      #pragma unroll
      for (int r = 0; r < 4; ++r)
        hst[nf][r] = h0[(size_t)lay * BB * NN + (size_t)(row0 + q4 * 4 + r) * NN + col];
    }
  }

  const size_t myring = (size_t)(lay * NRG + rg) * RD;
  const size_t upring = (size_t)((lay - 1) * NRG + rg) * RD;

  for (int t = 0; t < TS; ++t) {
    // ---- poll all join conditions in parallel across lanes ----
    unsigned tgt = 0;
    if (polltype == 1) tgt = (unsigned)t;                                  // q-join
    else if (polltype == 2) tgt = (unsigned)(t + 1);                       // p-join
    else if (polltype == 3 && t >= RD) tgt = (unsigned)(t - RD + 1);       // backpressure
    for (;;) {
      unsigned v = __hip_atomic_load(pollptr, __ATOMIC_RELAXED, __HIP_MEMORY_SCOPE_AGENT);
      if (__all(v >= tgt)) break;
    }

    // ---- stage q-tile (own h(t-1)) and p-tile (upstream n(t)) via sc1 x4 ----
    u4v qst[4], pst[4];
    if (t >= 1) {
      const unsigned short* src = ring + (myring + ((t - 1) & (RD - 1))) * (MR * NN);
      #pragma unroll
      for (int i = 0; i < 4; ++i) {
        const int chunk = i * 256 + tid;
        qst[i] = ldg_sc1_x4(src + (chunk >> 6) * NN + (chunk & 63) * 8);
      }
    }
    if (lay > 0) {
      const unsigned short* src = ring + (upring + (t & (RD - 1))) * (MR * NN);
      #pragma unroll
      for (int i = 0; i < 4; ++i) {
        const int chunk = i * 256 + tid;
        pst[i] = ldg_sc1_x4(src + (chunk >> 6) * NN + (chunk & 63) * 8);
      }
    }
    waitvm0();
    if (t >= 1) {
      #pragma unroll
      for (int i = 0; i < 4; ++i) {
        const int chunk = i * 256 + tid;
        *(u4v*)(qtile + (chunk >> 6) * LROW + (chunk & 63) * 8) = qst[i];
      }
    }
    if (lay > 0) {
      #pragma unroll
      for (int i = 0; i < 4; ++i) {
        const int chunk = i * 256 + tid;
        *(u4v*)(ptile + (chunk >> 6) * LROW + (chunk & 63) * 8) = pst[i];
      }
    }
    __syncthreads();   // vmcnt+lgkm drained for ALL waves -> staging reads done
    if (tid == 0 && lay > 0)   // safe for upstream to overwrite slot t
      __hip_atomic_store(selfdone, (unsigned)(t + 1), __ATOMIC_RELAXED,
                         __HIP_MEMORY_SCOPE_AGENT);

    // ---- MFMA phase: acc = x + p + q ----
    f4v zero4 = {0.f, 0.f, 0.f, 0.f};
    f4v acc[2] = {zero4, zero4};

    {  // x = data(t) @ Win  (K=64, normal cached loads)
      const float* dsrc = data + ((size_t)t * BB + row0 + lo) * 64 + q4 * 8;
      #pragma unroll
      for (int kk = 0; kk < 2; ++kk) {
        f4v a = *(const f4v*)(dsrc + kk * 32);
        f4v b = *(const f4v*)(dsrc + kk * 32 + 4);
        s8v av = pack8(a, b);
        acc[0] = MFMA16(av, WX[kk][0], acc[0]);
        acc[1] = MFMA16(av, WX[kk][1], acc[1]);
      }
    }
    if (lay > 0) {  // p = n_{l-1}(t) @ Whi
      #pragma unroll
      for (int kk = 0; kk < 16; ++kk) {
        s8v av = *(const s8v*)(ptile + lo * LROW + kk * 32 + q4 * 8);
        acc[0] = MFMA16(av, WI[kk][0], acc[0]);
        acc[1] = MFMA16(av, WI[kk][1], acc[1]);
      }
    }
    if (t == 0) {  // q from h0 directly (f32 -> bf16)
      const float* hsrc = h0 + (size_t)lay * BB * NN + (size_t)(row0 + lo) * NN + q4 * 8;
      #pragma unroll
      for (int kk = 0; kk < 16; ++kk) {
        f4v a = *(const f4v*)(hsrc + kk * 32);
        f4v b = *(const f4v*)(hsrc + kk * 32 + 4);
        s8v av = pack8(a, b);
        acc[0] = MFMA16(av, WH[kk][0], acc[0]);
        acc[1] = MFMA16(av, WH[kk][1], acc[1]);
      }
    } else {       // q = h(t-1) @ Whh from LDS
      #pragma unroll
      for (int kk = 0; kk < 16; ++kk) {
        s8v av = *(const s8v*)(qtile + lo * LROW + kk * 32 + q4 * 8);
        acc[0] = MFMA16(av, WH[kk][0], acc[0]);
        acc[1] = MFMA16(av, WH[kk][1], acc[1]);
      }
    }

    // ---- combine + produce: n = lrelu(0.5*h + 0.5*(acc + bias)) ----
    {
      unsigned short* rslot = ring + (myring + (t & (RD - 1))) * (MR * NN);
      #pragma unroll
      for (int nf = 0; nf < 2; ++nf) {
        const int col = cw + nf * 16 + lo;
        #pragma unroll
        for (int r = 0; r < 4; ++r) {
          const int row = q4 * 4 + r;
          float v = 0.5f * hst[nf][r] + 0.5f * (acc[nf][r] + biasv[nf]);
          v = (v >= 0.f) ? v : 0.01f * v;
          hst[nf][r] = v;
          stg_sc1_b16(rslot + (size_t)row * NN + col,
                      (unsigned)(unsigned short)f2bf(v));
          if (lay == 2 && t == TS - 1)
            hfinal[(size_t)(row0 + row) * NN + col] = v;
        }
      }
    }
    waitvm0();
    __syncthreads();   // every wave's sc1 stores drained -> publish
    if (tid == 0)
      __hip_atomic_store(selfprod, (unsigned)(t + 1), __ATOMIC_RELAXED,
                         __HIP_MEMORY_SCOPE_AGENT);
  }
}

// out[256,10] = hfinal @ Wfc + b_fc   (tiny f32 readout)
__global__ void readout_k(const float* __restrict__ hfinal, const float* __restrict__ Wfc,
                          const float* __restrict__ b_fc, float* __restrict__ out)
{
  const int row = blockIdx.x;
  const int lane = threadIdx.x;  // 64
  float a[10];
  #pragma unroll
  for (int c = 0; c < 10; ++c) a[c] = 0.f;
  for (int k = lane; k < NN; k += 64) {
    const float h = hfinal[(size_t)row * NN + k];
    const float* w = Wfc + (size_t)k * 10;
    #pragma unroll
    for (int c = 0; c < 10; ++c) a[c] += h * w[c];
  }
  #pragma unroll
  for (int off = 32; off > 0; off >>= 1) {
    #pragma unroll
    for (int c = 0; c < 10; ++c) a[c] += __shfl_down(a[c], off);
  }
  if (lane == 0) {
    #pragma unroll
    for (int c = 0; c < 10; ++c) out[row * 10 + c] = a[c] + b_fc[c];
  }
}

extern "C" void kernel_launch(void* const* d_in, const int* in_sizes, int n_in,
                              void* d_out, int out_size, void* d_ws, size_t ws_size,
                              hipStream_t stream) {
  (void)in_sizes; (void)n_in; (void)out_size; (void)ws_size;
  const float* data = (const float*)d_in[0];
  const float* h0   = (const float*)d_in[1];
  const float* Win  = (const float*)d_in[2];
  const float* b_in = (const float*)d_in[3];
  const float* Whh  = (const float*)d_in[4];
  const float* b_hh = (const float*)d_in[5];
  const float* Whi  = (const float*)d_in[6];
  const float* b_hi = (const float*)d_in[7];
  const float* Wfc  = (const float*)d_in[8];
  const float* b_fc = (const float*)d_in[9];

  // ws: rings (3 lay x 16 rg x RD x 16KB = 6 MB) | flags 64KB | hfinal 512KB
  unsigned short* ring = (unsigned short*)d_ws;
  const size_t ring_bytes = (size_t)3 * NRG * RD * MR * NN * 2;  // 6 MB
  unsigned* cnt = (unsigned*)((char*)d_ws + ring_bytes);
  float* hfinal = (float*)((char*)d_ws + ring_bytes + 65536);

  hipMemsetAsync(cnt, 0, 65536, stream);   // flags MUST start at 0 (ws is poisoned)
  hipLaunchKernelGGL(rnn_pipe, dim3(192), dim3(256), 0, stream,
                     data, h0, Win, b_in, Whh, b_hh, Whi, b_hi, ring, cnt, hfinal);
  hipLaunchKernelGGL(readout_k, dim3(256), dim3(64), 0, stream,
                     hfinal, Wfc, b_fc, (float*)d_out);
}